// Round 1
// baseline (164.718 us; speedup 1.0000x reference)
//
#include <hip/hip_runtime.h>

#define ROWS_PER_BLOCK 256
#define NCOLS 14
#define LDSTRIDE 15   // +1 pad: stride-15 row reads are conflict-free (odd stride)

__global__ __launch_bounds__(256)
void indicator_kernel(const float* __restrict__ state,
                      float* __restrict__ out,
                      int n_rows) {
    __shared__ float s_in[ROWS_PER_BLOCK * LDSTRIDE];   // 15360 B
    __shared__ float s_out[ROWS_PER_BLOCK * 3];         //  3072 B

    const int tid = threadIdx.x;
    const int block_row0 = blockIdx.x * ROWS_PER_BLOCK;
    const int rows_blk = min(ROWS_PER_BLOCK, n_rows - block_row0);

    // ---- Stage input rows into LDS with coalesced float4 loads ----
    // Block base byte offset = block_row0*56; for block_row0 multiple of 256
    // this is 16B-aligned (256*56 = 14336).
    const int n_floats = rows_blk * NCOLS;
    const int n_f4 = n_floats >> 2;
    const float4* in4 = (const float4*)(state + (size_t)block_row0 * NCOLS);
    for (int i = tid; i < n_f4; i += ROWS_PER_BLOCK) {
        float4 v = in4[i];
        int g = i * 4;
        float vv[4] = {v.x, v.y, v.z, v.w};
#pragma unroll
        for (int j = 0; j < 4; ++j) {
            int g2 = g + j;
            // lds index = row*15 + col = g2 + g2/14
            s_in[g2 + g2 / NCOLS] = vv[j];
        }
    }
    // tail (only possible if rows_blk odd; covered for generality)
    for (int i = (n_f4 << 2) + tid; i < n_floats; i += ROWS_PER_BLOCK) {
        s_in[i + i / NCOLS] = state[(size_t)block_row0 * NCOLS + i];
    }
    __syncthreads();

    // ---- Per-row compute ----
    if (tid < rows_blk) {
        const float* rp = &s_in[tid * LDSTRIDE];
        float ha_open  = rp[0];
        float ha_close = rp[1];
        float lwick    = rp[5];
        float uwick    = rp[6];
        float ma200    = rp[8];
        float stoch_rsi= rp[9];
        float stoch_sig= rp[10];
        float bb_up    = rp[11];
        float bb_mid   = rp[12];
        float bb_lo    = rp[13];

        bool is_bull = ha_close > ha_open;
        bool is_bear = ha_close < ha_open;
        float body   = fabsf(ha_close - ha_open);
        bool small_uw = uwick < 1e-6f;
        bool small_lw = lwick < 1e-6f;
        bool strong_bull = is_bull && (body > 0.5f) && small_uw;
        bool strong_bear = is_bear && (body > 0.5f) && small_lw;

        float ha2 = strong_bull ? 0.8f : 0.0f;
        float ha0 = strong_bear ? 0.8f : 0.0f;

        float band = bb_up - bb_lo;
        float bb_width = band / bb_mid;
        float pp = (ha_close - bb_lo) / band;
        bool sq  = bb_width < 0.1f;
        bool ex  = bb_width > 0.2f;
        bool sqex = sq && ex;   // structurally false; kept for fidelity

        bool pp_lo = pp < 0.2f;
        bool pp_hi = pp > 0.8f;
        float bb2 = 0.8f * (pp_lo ? 1.0f : 0.0f) + (sqex ? 0.9f : 0.0f);
        float bb0 = 0.8f * (pp_hi ? 1.0f : 0.0f) + (sqex ? 0.9f : 0.0f);

        float st2 = (stoch_rsi < 0.2f) ? 0.8f : 0.0f;
        float st0 = (stoch_rsi > 0.8f) ? 0.8f : 0.0f;

        bool ma_up = ma200 > 0.1f;
        bool ma_dn = ma200 < -0.1f;
        float ma2 = ma_up ? 0.7f : 0.0f;
        float ma0 = ma_dn ? 0.7f : 0.0f;

        bool st_dn = stoch_sig < -0.1f;
        bool st_up = stoch_sig > 0.1f;

        bool long_sig  = (strong_bull && ma_up && st_dn) ||
                         (strong_bull && ma_up && pp_lo) ||
                         (strong_bull && st_dn && pp_lo) ||
                         (ma_up && st_dn && pp_lo);
        bool short_sig = (strong_bear && ma_dn && st_up) ||
                         (strong_bear && ma_dn && pp_hi) ||
                         (strong_bear && st_up && pp_hi) ||
                         (ma_dn && st_up && pp_hi);

        float col0 = ha0 + ma0 + st0 + bb0 + (short_sig ? 1.8f : 0.0f);
        float col2 = ha2 + ma2 + st2 + bb2 + (long_sig  ? 1.8f : 0.0f);
        const float col1 = 1.5f;

        float m = fmaxf(col1, fmaxf(col0, col2));
        float e0 = __expf(col0 - m);
        float e1 = __expf(col1 - m);
        float e2 = __expf(col2 - m);
        float inv = 1.0f / (e0 + e1 + e2);

        s_out[tid * 3 + 0] = e0 * inv;
        s_out[tid * 3 + 1] = e1 * inv;
        s_out[tid * 3 + 2] = e2 * inv;
    }
    __syncthreads();

    // ---- Coalesced float4 output store ----
    // out base byte offset = block_row0*12; multiple of 3072 → 16B-aligned.
    const int n_out = rows_blk * 3;
    const int n_o4 = n_out >> 2;
    float* outb = out + (size_t)block_row0 * 3;
    float4* out4 = (float4*)outb;
    const float4* so4 = (const float4*)s_out;
    for (int i = tid; i < n_o4; i += ROWS_PER_BLOCK) {
        out4[i] = so4[i];
    }
    for (int i = (n_o4 << 2) + tid; i < n_out; i += ROWS_PER_BLOCK) {
        outb[i] = s_out[i];
    }
}

extern "C" void kernel_launch(void* const* d_in, const int* in_sizes, int n_in,
                              void* d_out, int out_size, void* d_ws, size_t ws_size,
                              hipStream_t stream) {
    const float* state = (const float*)d_in[0];
    float* out = (float*)d_out;
    int n_rows = in_sizes[0] / NCOLS;
    int grid = (n_rows + ROWS_PER_BLOCK - 1) / ROWS_PER_BLOCK;
    indicator_kernel<<<grid, ROWS_PER_BLOCK, 0, stream>>>(state, out, n_rows);
}

// Round 3
// 157.270 us; speedup vs baseline: 1.0474x; 1.0474x over previous
//
#include <hip/hip_runtime.h>

#define NCOLS 14
#define RPB 512          // rows per block
#define THREADS 256
#define LDSTRIDE 15      // +1 pad: stride-15 row reads are 2-way max (free per m136)

typedef float f4 __attribute__((ext_vector_type(4)));  // clang vector: works with nontemporal builtins

__global__ __launch_bounds__(THREADS)
void indicator_kernel(const float* __restrict__ state,
                      float* __restrict__ out,
                      int n_rows) {
    __shared__ float s_in[RPB * LDSTRIDE];   // 30720 B
    __shared__ float s_out[RPB * 3];         //  6144 B

    const int tid = threadIdx.x;
    const int row0 = blockIdx.x * RPB;
    const int rows_blk = min(RPB, n_rows - row0);

    // Block input base byte offset = row0*56 = blockIdx*28672 → 16B-aligned.
    const f4* in4 = (const f4*)(state + (size_t)row0 * NCOLS);

    if (rows_blk == RPB) {
        // Fast path: 512*14 = 7168 floats = 1792 f4; 7 per thread,
        // all loads issued before any LDS write (max memory-level parallelism).
        f4 v[7];
#pragma unroll
        for (int k = 0; k < 7; ++k)
            v[k] = __builtin_nontemporal_load(&in4[tid + THREADS * k]);
#pragma unroll
        for (int k = 0; k < 7; ++k) {
            int g = 4 * (tid + THREADS * k);
#pragma unroll
            for (int j = 0; j < 4; ++j) {
                int g2 = g + j;
                s_in[g2 + g2 / NCOLS] = v[k][j];   // idx = row*15 + col
            }
        }
    } else {
        // Generic tail path (last block only)
        const int n_floats = rows_blk * NCOLS;
        const int n_f4 = n_floats >> 2;
        for (int i = tid; i < n_f4; i += THREADS) {
            f4 v = in4[i];
            int g = i * 4;
#pragma unroll
            for (int j = 0; j < 4; ++j) {
                int g2 = g + j;
                s_in[g2 + g2 / NCOLS] = v[j];
            }
        }
        for (int i = (n_f4 << 2) + tid; i < n_floats; i += THREADS)
            s_in[i + i / NCOLS] = state[(size_t)row0 * NCOLS + i];
    }
    __syncthreads();

    // ---- Per-row compute: 2 rows per thread ----
#pragma unroll
    for (int rr = 0; rr < 2; ++rr) {
        const int r = tid + THREADS * rr;
        if (r < rows_blk) {
            const float* rp = &s_in[r * LDSTRIDE];
            float ha_open  = rp[0];
            float ha_close = rp[1];
            float lwick    = rp[5];
            float uwick    = rp[6];
            float ma200    = rp[8];
            float stoch_rsi= rp[9];
            float stoch_sig= rp[10];
            float bb_up    = rp[11];
            float bb_mid   = rp[12];
            float bb_lo    = rp[13];

            bool is_bull = ha_close > ha_open;
            bool is_bear = ha_close < ha_open;
            float body   = fabsf(ha_close - ha_open);
            bool small_uw = uwick < 1e-6f;
            bool small_lw = lwick < 1e-6f;
            bool strong_bull = is_bull && (body > 0.5f) && small_uw;
            bool strong_bear = is_bear && (body > 0.5f) && small_lw;

            float ha2 = strong_bull ? 0.8f : 0.0f;
            float ha0 = strong_bear ? 0.8f : 0.0f;

            float band = bb_up - bb_lo;
            float bb_width = band / bb_mid;
            float pp = (ha_close - bb_lo) / band;
            bool sqex = (bb_width < 0.1f) && (bb_width > 0.2f);  // structurally false; fidelity

            bool pp_lo = pp < 0.2f;
            bool pp_hi = pp > 0.8f;
            float bb2 = 0.8f * (pp_lo ? 1.0f : 0.0f) + (sqex ? 0.9f : 0.0f);
            float bb0 = 0.8f * (pp_hi ? 1.0f : 0.0f) + (sqex ? 0.9f : 0.0f);

            float st2 = (stoch_rsi < 0.2f) ? 0.8f : 0.0f;
            float st0 = (stoch_rsi > 0.8f) ? 0.8f : 0.0f;

            bool ma_up = ma200 > 0.1f;
            bool ma_dn = ma200 < -0.1f;
            float ma2 = ma_up ? 0.7f : 0.0f;
            float ma0 = ma_dn ? 0.7f : 0.0f;

            bool st_dn = stoch_sig < -0.1f;
            bool st_up = stoch_sig > 0.1f;

            bool long_sig  = (strong_bull && ma_up && st_dn) ||
                             (strong_bull && ma_up && pp_lo) ||
                             (strong_bull && st_dn && pp_lo) ||
                             (ma_up && st_dn && pp_lo);
            bool short_sig = (strong_bear && ma_dn && st_up) ||
                             (strong_bear && ma_dn && pp_hi) ||
                             (strong_bear && st_up && pp_hi) ||
                             (ma_dn && st_up && pp_hi);

            float col0 = ha0 + ma0 + st0 + bb0 + (short_sig ? 1.8f : 0.0f);
            float col2 = ha2 + ma2 + st2 + bb2 + (long_sig  ? 1.8f : 0.0f);
            const float col1 = 1.5f;

            float m = fmaxf(col1, fmaxf(col0, col2));
            float e0 = __expf(col0 - m);
            float e1 = __expf(col1 - m);
            float e2 = __expf(col2 - m);
            float inv = 1.0f / (e0 + e1 + e2);

            s_out[r * 3 + 0] = e0 * inv;
            s_out[r * 3 + 1] = e1 * inv;
            s_out[r * 3 + 2] = e2 * inv;
        }
    }
    __syncthreads();

    // ---- Coalesced output store (base = blockIdx*6144 B → 16B-aligned) ----
    const int n_out = rows_blk * 3;
    const int n_o4 = n_out >> 2;
    float* outb = out + (size_t)row0 * 3;
    f4* out4 = (f4*)outb;
    const f4* so4 = (const f4*)s_out;
    if (rows_blk == RPB) {
        // 512*3/4 = 384 f4: tid, plus tid+256 for tid<128
        __builtin_nontemporal_store(so4[tid], &out4[tid]);
        if (tid < 384 - THREADS)
            __builtin_nontemporal_store(so4[tid + THREADS], &out4[tid + THREADS]);
    } else {
        for (int i = tid; i < n_o4; i += THREADS) out4[i] = so4[i];
        for (int i = (n_o4 << 2) + tid; i < n_out; i += THREADS) outb[i] = s_out[i];
    }
}

extern "C" void kernel_launch(void* const* d_in, const int* in_sizes, int n_in,
                              void* d_out, int out_size, void* d_ws, size_t ws_size,
                              hipStream_t stream) {
    const float* state = (const float*)d_in[0];
    float* out = (float*)d_out;
    int n_rows = in_sizes[0] / NCOLS;
    int grid = (n_rows + RPB - 1) / RPB;
    indicator_kernel<<<grid, THREADS, 0, stream>>>(state, out, n_rows);
}